// Round 2
// baseline (787.394 us; speedup 1.0000x reference)
//
#include <hip/hip_runtime.h>

typedef __attribute__((ext_vector_type(8))) short s8v;
typedef __attribute__((ext_vector_type(4))) short s4v;
typedef __attribute__((ext_vector_type(4))) float f4v;

constexpr int SEQ = 2048;
constexpr int EMB = 512;
constexpr int BATCH = 8;
constexpr int BS = BATCH * SEQ;  // 16384

#define DEVINL __device__ __forceinline__

DEVINL float bf2f(short s) {
    union { unsigned u; float f; } v;
    v.u = ((unsigned)(unsigned short)s) << 16;
    return v.f;
}
DEVINL short f2bf(float f) {
    union { float f; unsigned u; } v; v.f = f;
    unsigned u = v.u;
    return (short)((u + 0x7FFFu + ((u >> 16) & 1u)) >> 16);
}
DEVINL float sigmf(float x) {
    return __builtin_amdgcn_rcpf(1.0f + __expf(-x));
}
DEVINL f4v mfma16(s8v a, s8v b, f4v c) {
    return __builtin_amdgcn_mfma_f32_16x16x32_bf16(a, b, c, 0, 0, 0);
}
DEVINL s8v pack8(float4 a, float4 b) {
    s8v o;
    o[0] = f2bf(a.x); o[1] = f2bf(a.y); o[2] = f2bf(a.z); o[3] = f2bf(a.w);
    o[4] = f2bf(b.x); o[5] = f2bf(b.y); o[6] = f2bf(b.z); o[7] = f2bf(b.w);
    return o;
}

// ---------------- prep kernels ----------------

__global__ __launch_bounds__(256) void prep_tn(const float* __restrict__ x,
                                               short* __restrict__ y) {
    int row = blockIdx.x * 4 + (threadIdx.x >> 6);
    int lane = threadIdx.x & 63;
    const float* p = x + (size_t)row * EMB + lane * 8;
    float4 a = *(const float4*)p;
    float4 b = *(const float4*)(p + 4);
    float ss = a.x*a.x + a.y*a.y + a.z*a.z + a.w*a.w
             + b.x*b.x + b.y*b.y + b.z*b.z + b.w*b.w;
#pragma unroll
    for (int m = 32; m >= 1; m >>= 1) ss += __shfl_xor(ss, m);
    float inv = __builtin_amdgcn_rcpf(fmaxf(sqrtf(ss), 1e-12f));
    float4 sa = make_float4(a.x*inv, a.y*inv, a.z*inv, a.w*inv);
    float4 sb = make_float4(b.x*inv, b.y*inv, b.z*inv, b.w*inv);
    *(s8v*)(y + (size_t)row * EMB + lane * 8) = pack8(sa, sb);
}

__global__ __launch_bounds__(256) void cast8(const float* __restrict__ x,
                                             short* __restrict__ y, int n8) {
    int i = blockIdx.x * 256 + threadIdx.x;
    if (i >= n8) return;
    const float* p = x + (size_t)i * 8;
    float4 a = *(const float4*)p;
    float4 b = *(const float4*)(p + 4);
    *(s8v*)(y + (size_t)i * 8) = pack8(a, b);
}

// W [512k][512n] f32 -> WT [n][k] bf16
__global__ __launch_bounds__(256) void castWT(const float* __restrict__ W,
                                              short* __restrict__ WT) {
    int t = blockIdx.x * 256 + threadIdx.x;  // 32768 threads
    int n = t >> 6;
    int k0 = (t & 63) * 8;
    s8v o;
#pragma unroll
    for (int e = 0; e < 8; e++) o[e] = f2bf(W[(size_t)(k0 + e) * EMB + n]);
    *(s8v*)(WT + (size_t)n * EMB + k0) = o;
}

// ---------------- generic 512-col GEMM with fused epilogues ----------------
template <int EPI>
__global__ __launch_bounds__(256) void gemm512(
    const short* __restrict__ A, const short* __restrict__ WT,
    const float* __restrict__ bias, const float* __restrict__ resid,
    float* __restrict__ outf, short* __restrict__ outb,
    const float* __restrict__ gam, const float* __restrict__ bet) {
    __shared__ float lsum[32];
    __shared__ float lsq[32];
    const int tid = threadIdx.x;
    const int wave = tid >> 6, lane = tid & 63;
    const int lr = lane & 15, kg = lane >> 4;
    const int rowbase = blockIdx.x * 32;
    const int colbase = wave * 128;
    if constexpr (EPI >= 2) {
        if (tid < 32) { lsum[tid] = 0.f; lsq[tid] = 0.f; }
        __syncthreads();
    }
    f4v acc[2][8] = {};
    const short* Ap0 = A + (size_t)(rowbase + lr) * EMB + kg * 8;
    const short* Ap1 = Ap0 + 16 * EMB;
    const short* Bp  = WT + (size_t)(colbase + lr) * EMB + kg * 8;
    for (int kk = 0; kk < EMB; kk += 32) {
        s8v a0 = *(const s8v*)(Ap0 + kk);
        s8v a1 = *(const s8v*)(Ap1 + kk);
#pragma unroll
        for (int n = 0; n < 8; n++) {
            s8v bv = *(const s8v*)(Bp + (size_t)n * 16 * EMB + kk);
            acc[0][n] = mfma16(a0, bv, acc[0][n]);
            acc[1][n] = mfma16(a1, bv, acc[1][n]);
        }
    }
    float bcol[8];
#pragma unroll
    for (int n = 0; n < 8; n++) bcol[n] = bias[colbase + n * 16 + lr];

    if constexpr (EPI == 0) {
#pragma unroll
        for (int m = 0; m < 2; m++) {
            int grow0 = rowbase + m * 16 + kg * 4;
            int bb = grow0 >> 11;
            int s0 = grow0 & (SEQ - 1);
#pragma unroll
            for (int n = 0; n < 8; n++) {
                int col = colbase + n * 16 + lr;
                s4v o;
#pragma unroll
                for (int r = 0; r < 4; r++) o[r] = f2bf(acc[m][n][r] + bcol[n]);
                *(s4v*)(outb + ((size_t)(bb * EMB + col)) * SEQ + s0) = o;
            }
        }
    } else if constexpr (EPI == 1) {
#pragma unroll
        for (int m = 0; m < 2; m++)
#pragma unroll
            for (int n = 0; n < 8; n++) {
                int col = colbase + n * 16 + lr;
#pragma unroll
                for (int r = 0; r < 4; r++) {
                    int grow = rowbase + m * 16 + kg * 4 + r;
                    outb[(size_t)grow * EMB + col] =
                        f2bf(fmaxf(acc[m][n][r] + bcol[n], 0.f));
                }
            }
    } else {
        float sm[2][4] = {}, sq2[2][4] = {};
#pragma unroll
        for (int m = 0; m < 2; m++)
#pragma unroll
            for (int n = 0; n < 8; n++) {
                int col = colbase + n * 16 + lr;
#pragma unroll
                for (int r = 0; r < 4; r++) {
                    int grow = rowbase + m * 16 + kg * 4 + r;
                    float v = acc[m][n][r] + bcol[n] + resid[(size_t)grow * EMB + col];
                    acc[m][n][r] = v;
                    sm[m][r] += v;
                    sq2[m][r] += v * v;
                }
            }
#pragma unroll
        for (int m = 0; m < 2; m++)
#pragma unroll
            for (int r = 0; r < 4; r++) {
                float s = sm[m][r], t = sq2[m][r];
                s += __shfl_xor(s, 1); t += __shfl_xor(t, 1);
                s += __shfl_xor(s, 2); t += __shfl_xor(t, 2);
                s += __shfl_xor(s, 4); t += __shfl_xor(t, 4);
                s += __shfl_xor(s, 8); t += __shfl_xor(t, 8);
                if (lr == 0) {
                    atomicAdd(&lsum[m * 16 + kg * 4 + r], s);
                    atomicAdd(&lsq[m * 16 + kg * 4 + r], t);
                }
            }
        __syncthreads();
#pragma unroll
        for (int m = 0; m < 2; m++)
#pragma unroll
            for (int r = 0; r < 4; r++) {
                int rowl = m * 16 + kg * 4 + r;
                int grow = rowbase + rowl;
                float mean = lsum[rowl] * (1.f / EMB);
                float var = lsq[rowl] * (1.f / EMB) - mean * mean;
                float rstd = rsqrtf(var + 1e-5f);
#pragma unroll
                for (int n = 0; n < 8; n++) {
                    int col = colbase + n * 16 + lr;
                    float yv = (acc[m][n][r] - mean) * rstd * gam[col] + bet[col];
                    outf[(size_t)grow * EMB + col] = yv;
                    if constexpr (EPI == 2)
                        outb[(size_t)grow * EMB + col] = f2bf(yv);
                }
            }
    }
}

// ---------------- fused similarity-attention kernel (recompute, no S1) ----------------
// s1 = f(c) via 257-entry LDS table (f = exp(avg4sigmoid), c in [-1.02,1.02]).
// Sweep 1: c-MFMA -> Z1 row sums (s1 discarded).
// Sweep 2: re-compute c, q = (j>i) ? 1 + x + x^2/2 (x = s1/Z1) : 0  (row SEQ-1: all 1),
//          q -> swizzled Qbuf -> PV MFMA against Vt; normalize by Z2 = sum(q_bf16).
__global__ __launch_bounds__(256) void attn_kernel(
    const short* __restrict__ TN, const short* __restrict__ Vt,
    short* __restrict__ ATT) {
    __shared__ __attribute__((aligned(16))) short Abuf[32 * EMB];   // 32KB swizzled
    __shared__ __attribute__((aligned(16))) short Qbuf[32 * 256];   // 16KB swizzled
    __shared__ float ftab[257];
    __shared__ float z1[32];
    __shared__ float z2[32];

    int bid = blockIdx.x;
    int swz = (bid & 7) * 64 + (bid >> 3);  // batch -> XCD locality
    int b = swz >> 6;
    int ibase = (swz & 63) * 32;
    int tid = threadIdx.x;
    int wave = tid >> 6, lane = tid & 63, lr = lane & 15, kg = lane >> 4;

    // build lookup table for s1 = exp(0.25*(sig(c)+sig(c^2)+sig(exp(c-1))+sig(c/2+.5)))
    for (int i = tid; i < 257; i += 256) {
        float x = -1.02f + (float)i * (2.04f / 256.0f);
        float aw = 0.25f * (sigmf(x) + sigmf(x * x) + sigmf(__expf(x - 1.0f)) +
                            sigmf(0.5f * x + 0.5f));
        ftab[i] = __expf(aw);
    }

    const short* TNb = TN + (size_t)b * SEQ * EMB;
    const short* TNi = TNb + (size_t)ibase * EMB;

    // stage A tile (32 x 512) into LDS, XOR-swizzled by row
#pragma unroll
    for (int g = 0; g < 8; g++) {
        int idx = g * 256 + tid;
        int row = idx >> 6, c16 = idx & 63;
        int boff = ((row << 10) | (c16 << 4)) ^ ((row & 7) << 4);
        *(s8v*)((char*)Abuf + boff) = *(const s8v*)(TNi + (size_t)row * EMB + c16 * 8);
    }
    if (tid < 32) { z1[tid] = 0.f; z2[tid] = 0.f; }
    __syncthreads();

    // table lookup: s1 = f(c), linear interp
    auto lookup = [&](float c) -> float {
        float t = fmaf(c, 256.0f / 2.04f, 1.02f * 256.0f / 2.04f);
        t = fminf(fmaxf(t, 0.0f), 255.99f);
        int i0 = (int)t;
        float fr = t - (float)i0;
        float lo = ftab[i0], hi = ftab[i0 + 1];
        return fmaf(fr, hi - lo, lo);
    };

    // ---- SWEEP 1: Z1 ----
    float z1p[2][4] = {};
    for (int jb = 0; jb < SEQ; jb += 512) {
        int jcol = jb + wave * 128;
        f4v acc[2][8] = {};
        for (int kk = 0; kk < EMB; kk += 32) {
            s8v a0, a1;
            {
                int boff = ((lr << 10) | ((kk + kg * 8) << 1)) ^ ((lr & 7) << 4);
                a0 = *(const s8v*)((char*)Abuf + boff);
            }
            {
                int row = 16 + lr;
                int boff = ((row << 10) | ((kk + kg * 8) << 1)) ^ ((row & 7) << 4);
                a1 = *(const s8v*)((char*)Abuf + boff);
            }
#pragma unroll
            for (int n = 0; n < 8; n++) {
                s8v bv = *(const s8v*)(TNb + (size_t)(jcol + n * 16 + lr) * EMB + kk + kg * 8);
                acc[0][n] = mfma16(a0, bv, acc[0][n]);
                acc[1][n] = mfma16(a1, bv, acc[1][n]);
            }
        }
#pragma unroll
        for (int m = 0; m < 2; m++)
#pragma unroll
            for (int n = 0; n < 8; n++)
#pragma unroll
                for (int r = 0; r < 4; r++)
                    z1p[m][r] += lookup(acc[m][n][r]);
    }
#pragma unroll
    for (int m = 0; m < 2; m++)
#pragma unroll
        for (int r = 0; r < 4; r++) {
            float s = z1p[m][r];
            s += __shfl_xor(s, 1);
            s += __shfl_xor(s, 2);
            s += __shfl_xor(s, 4);
            s += __shfl_xor(s, 8);
            if (lr == 0) atomicAdd(&z1[m * 16 + kg * 4 + r], s);
        }
    __syncthreads();

    float invz1v[2][4];
#pragma unroll
    for (int m = 0; m < 2; m++)
#pragma unroll
        for (int r = 0; r < 4; r++)
            invz1v[m][r] = __builtin_amdgcn_rcpf(z1[m * 16 + kg * 4 + r]);

    // ---- SWEEP 2: recompute c, build Q tiles, PV ----
    f4v pv[2][8] = {};
    float z2p[2][4] = {};
    const short* Vtw = Vt + (size_t)b * EMB * SEQ + (size_t)(wave * 128 + lr) * SEQ;

    for (int jb = 0; jb < SEQ; jb += 256) {
        int jcol = jb + wave * 64;
        f4v cacc[2][4] = {};
        for (int kk = 0; kk < EMB; kk += 32) {
            s8v a0, a1;
            {
                int boff = ((lr << 10) | ((kk + kg * 8) << 1)) ^ ((lr & 7) << 4);
                a0 = *(const s8v*)((char*)Abuf + boff);
            }
            {
                int row = 16 + lr;
                int boff = ((row << 10) | ((kk + kg * 8) << 1)) ^ ((row & 7) << 4);
                a1 = *(const s8v*)((char*)Abuf + boff);
            }
#pragma unroll
            for (int n = 0; n < 4; n++) {
                s8v bv = *(const s8v*)(TNb + (size_t)(jcol + n * 16 + lr) * EMB + kk + kg * 8);
                cacc[0][n] = mfma16(a0, bv, cacc[0][n]);
                cacc[1][n] = mfma16(a1, bv, cacc[1][n]);
            }
        }
        __syncthreads();  // previous PV reads of Qbuf complete
#pragma unroll
        for (int m = 0; m < 2; m++)
#pragma unroll
            for (int n = 0; n < 4; n++)
#pragma unroll
                for (int r = 0; r < 4; r++) {
                    int il = m * 16 + kg * 4 + r;
                    int i = ibase + il;
                    int j = jcol + n * 16 + lr;
                    float s1 = lookup(cacc[m][n][r]);
                    float x = s1 * invz1v[m][r];
                    float qq;
                    if (i == SEQ - 1) qq = 1.0f;
                    else if (j > i) qq = fmaf(x, fmaf(0.5f, x, 1.0f), 1.0f);
                    else qq = 0.0f;
                    short qb = f2bf(qq);
                    z2p[m][r] += bf2f(qb);
                    int jj = wave * 64 + n * 16 + lr;
                    int boff = ((il << 9) | (jj << 1)) ^ ((il & 7) << 4);
                    *(short*)((char*)Qbuf + boff) = qb;
                }
        __syncthreads();  // Qbuf fully written
#pragma unroll
        for (int ks = 0; ks < 8; ks++) {
            s8v a0, a1;
            {
                int boff = ((lr << 9) | ((ks * 32 + kg * 8) << 1)) ^ ((lr & 7) << 4);
                a0 = *(const s8v*)((char*)Qbuf + boff);
            }
            {
                int row = 16 + lr;
                int boff = ((row << 9) | ((ks * 32 + kg * 8) << 1)) ^ ((row & 7) << 4);
                a1 = *(const s8v*)((char*)Qbuf + boff);
            }
#pragma unroll
            for (int n = 0; n < 8; n++) {
                s8v bv = *(const s8v*)(Vtw + (size_t)n * 16 * SEQ + jb + ks * 32 + kg * 8);
                pv[0][n] = mfma16(a0, bv, pv[0][n]);
                pv[1][n] = mfma16(a1, bv, pv[1][n]);
            }
        }
    }
#pragma unroll
    for (int m = 0; m < 2; m++)
#pragma unroll
        for (int r = 0; r < 4; r++) {
            float s = z2p[m][r];
            s += __shfl_xor(s, 1);
            s += __shfl_xor(s, 2);
            s += __shfl_xor(s, 4);
            s += __shfl_xor(s, 8);
            if (lr == 0) atomicAdd(&z2[m * 16 + kg * 4 + r], s);
        }
    __syncthreads();

    short* ATTb = ATT + ((size_t)b * SEQ + ibase) * EMB;
#pragma unroll
    for (int m = 0; m < 2; m++)
#pragma unroll
        for (int r = 0; r < 4; r++) {
            int rowl = m * 16 + kg * 4 + r;
            float wsc = __builtin_amdgcn_rcpf(z2[rowl]);
#pragma unroll
            for (int n = 0; n < 8; n++)
                ATTb[(size_t)rowl * EMB + wave * 128 + n * 16 + lr] =
                    f2bf(pv[m][n][r] * wsc);
        }
}

// ---------------- launch ----------------

extern "C" void kernel_launch(void* const* d_in, const int* in_sizes, int n_in,
                              void* d_out, int out_size, void* d_ws, size_t ws_size,
                              hipStream_t stream) {
    (void)in_sizes; (void)n_in; (void)out_size; (void)ws_size;
    const float* q     = (const float*)d_in[0];
    const float* k     = (const float*)d_in[1];
    const float* traj  = (const float*)d_in[2];
    const float* v_W   = (const float*)d_in[3];
    const float* v_b   = (const float*)d_in[4];
    const float* out_W = (const float*)d_in[5];
    const float* out_b = (const float*)d_in[6];
    const float* ln1_g = (const float*)d_in[7];
    const float* ln1_b = (const float*)d_in[8];
    const float* w1    = (const float*)d_in[9];
    const float* b1    = (const float*)d_in[10];
    const float* w2    = (const float*)d_in[11];
    const float* b2    = (const float*)d_in[12];
    const float* ln2_g = (const float*)d_in[13];
    const float* ln2_b = (const float*)d_in[14];

    char* ws = (char*)d_ws;
    const size_t MB = 1u << 20;
    short* TN  = (short*)(ws);            // 16MB bf16 normalized trajectories
    short* KB  = (short*)(ws + 16 * MB);  // 16MB bf16 k  (dead after V-gemm)
    short* ATT = KB;                      // reuse region for attended (bf16)
    short* WvT = (short*)(ws + 32 * MB);  // 4 x 0.5MB transposed bf16 weights
    short* WoT = WvT + 512 * 512;
    short* W1T = WoT + 512 * 512;
    short* W2T = W1T + 512 * 512;
    short* Vt  = (short*)(ws + 34 * MB);  // 16MB bf16 V transposed [b][e][s]
    float* X   = (float*)(ws + 50 * MB);  // 32MB f32 x (post-LN1)
    short* Xbf = (short*)(ws + 82 * MB);  // 16MB bf16 x
    short* H1  = (short*)(ws + 98 * MB);  // 16MB bf16 relu(x@w1+b1)

    prep_tn<<<BS / 4, 256, 0, stream>>>(traj, TN);
    cast8<<<BS * EMB / 8 / 256, 256, 0, stream>>>(k, KB, BS * EMB / 8);
    castWT<<<128, 256, 0, stream>>>(v_W, WvT);
    castWT<<<128, 256, 0, stream>>>(out_W, WoT);
    castWT<<<128, 256, 0, stream>>>(w1, W1T);
    castWT<<<128, 256, 0, stream>>>(w2, W2T);

    // V = k @ v_W + v_b  -> Vt (transposed bf16)
    gemm512<0><<<BS / 32, 256, 0, stream>>>(KB, WvT, v_b, nullptr, nullptr, Vt,
                                            nullptr, nullptr);
    // similarity + double softmax + PV -> ATT
    attn_kernel<<<BS / 32, 256, 0, stream>>>(TN, Vt, ATT);
    // attn_out = ATT @ out_W + out_b; x = LN1(q + attn_out) -> X, Xbf
    gemm512<2><<<BS / 32, 256, 0, stream>>>(ATT, WoT, out_b, q, X, Xbf, ln1_g,
                                            ln1_b);
    // h1 = relu(x @ w1 + b1) -> H1
    gemm512<1><<<BS / 32, 256, 0, stream>>>(Xbf, W1T, b1, nullptr, nullptr, H1,
                                            nullptr, nullptr);
    // out = LN2(x + h1 @ w2 + b2) -> d_out
    gemm512<3><<<BS / 32, 256, 0, stream>>>(H1, W2T, b2, X, (float*)d_out,
                                            nullptr, ln2_g, ln2_b);
}

// Round 3
// 238.300 us; speedup vs baseline: 3.3042x; 3.3042x over previous
//
#include <hip/hip_runtime.h>

typedef __attribute__((ext_vector_type(8))) short s8v;
typedef __attribute__((ext_vector_type(4))) short s4v;
typedef __attribute__((ext_vector_type(4))) float f4v;

constexpr int SEQ = 2048;
constexpr int EMB = 512;
constexpr int BATCH = 8;
constexpr int BS = BATCH * SEQ;  // 16384
constexpr int NCH = 32;          // scan chunks per batch (64 rows each)

#define DEVINL __device__ __forceinline__

DEVINL float bf2f(short s) {
    union { unsigned u; float f; } v;
    v.u = ((unsigned)(unsigned short)s) << 16;
    return v.f;
}
DEVINL short f2bf(float f) {
    union { float f; unsigned u; } v; v.f = f;
    unsigned u = v.u;
    return (short)((u + 0x7FFFu + ((u >> 16) & 1u)) >> 16);
}
DEVINL f4v mfma16(s8v a, s8v b, f4v c) {
    return __builtin_amdgcn_mfma_f32_16x16x32_bf16(a, b, c, 0, 0, 0);
}
DEVINL s8v pack8(float4 a, float4 b) {
    s8v o;
    o[0] = f2bf(a.x); o[1] = f2bf(a.y); o[2] = f2bf(a.z); o[3] = f2bf(a.w);
    o[4] = f2bf(b.x); o[5] = f2bf(b.y); o[6] = f2bf(b.z); o[7] = f2bf(b.w);
    return o;
}

// ---------------- prep kernels ----------------

__global__ __launch_bounds__(256) void cast8(const float* __restrict__ x,
                                             short* __restrict__ y, int n8) {
    int i = blockIdx.x * 256 + threadIdx.x;
    if (i >= n8) return;
    const float* p = x + (size_t)i * 8;
    float4 a = *(const float4*)p;
    float4 b = *(const float4*)(p + 4);
    *(s8v*)(y + (size_t)i * 8) = pack8(a, b);
}

// W [512k][512n] f32 -> WT [n][k] bf16
__global__ __launch_bounds__(256) void castWT(const float* __restrict__ W,
                                              short* __restrict__ WT) {
    int t = blockIdx.x * 256 + threadIdx.x;  // 32768 threads
    int n = t >> 6;
    int k0 = (t & 63) * 8;
    s8v o;
#pragma unroll
    for (int e = 0; e < 8; e++) o[e] = f2bf(W[(size_t)(k0 + e) * EMB + n]);
    *(s8v*)(WT + (size_t)n * EMB + k0) = o;
}

// bc[n] = sum_m v_b[m] * out_W[m][n] + out_b[n]
__global__ __launch_bounds__(256) void bias_combine(
    const float* __restrict__ v_b, const float* __restrict__ out_W,
    const float* __restrict__ out_b, float* __restrict__ bc) {
    int n = blockIdx.x * 256 + threadIdx.x;
    float acc = 0.f;
    for (int m = 0; m < EMB; m++) acc += v_b[m] * out_W[(size_t)m * EMB + n];
    bc[n] = acc + out_b[n];
}

// ---------------- generic 512-col GEMM with fused epilogues ----------------
// C[rows x 512] = A_bf16[rows x 512] @ WT^T (+ bias), block = 32 rows,
// 4 waves x 128 cols.
// EPI 1: +bias, relu, store bf16 row-major
// EPI 3: +bias +resid, LayerNorm -> outf f32
// EPI 5: no bias, store bf16 TRANSPOSED with stride 512 (outb[n][row])
// EPI 6: +bias, store bf16 row-major
template <int EPI>
__global__ __launch_bounds__(256) void gemm512(
    const short* __restrict__ A, const short* __restrict__ WT,
    const float* __restrict__ bias, const float* __restrict__ resid,
    float* __restrict__ outf, short* __restrict__ outb,
    const float* __restrict__ gam, const float* __restrict__ bet) {
    __shared__ float lsum[32];
    __shared__ float lsq[32];
    const int tid = threadIdx.x;
    const int wave = tid >> 6, lane = tid & 63;
    const int lr = lane & 15, kg = lane >> 4;
    const int rowbase = blockIdx.x * 32;
    const int colbase = wave * 128;
    if constexpr (EPI == 3) {
        if (tid < 32) { lsum[tid] = 0.f; lsq[tid] = 0.f; }
        __syncthreads();
    }
    f4v acc[2][8] = {};
    const short* Ap0 = A + (size_t)(rowbase + lr) * EMB + kg * 8;
    const short* Ap1 = Ap0 + 16 * EMB;
    const short* Bp  = WT + (size_t)(colbase + lr) * EMB + kg * 8;
    for (int kk = 0; kk < EMB; kk += 32) {
        s8v a0 = *(const s8v*)(Ap0 + kk);
        s8v a1 = *(const s8v*)(Ap1 + kk);
#pragma unroll
        for (int n = 0; n < 8; n++) {
            s8v bv = *(const s8v*)(Bp + (size_t)n * 16 * EMB + kk);
            acc[0][n] = mfma16(a0, bv, acc[0][n]);
            acc[1][n] = mfma16(a1, bv, acc[1][n]);
        }
    }
    float bcol[8];
    if constexpr (EPI != 5) {
#pragma unroll
        for (int n = 0; n < 8; n++) bcol[n] = bias[colbase + n * 16 + lr];
    }

    if constexpr (EPI == 5) {
#pragma unroll
        for (int m = 0; m < 2; m++) {
            int grow0 = rowbase + m * 16 + kg * 4;
#pragma unroll
            for (int n = 0; n < 8; n++) {
                int col = colbase + n * 16 + lr;
                s4v o;
#pragma unroll
                for (int r = 0; r < 4; r++) o[r] = f2bf(acc[m][n][r]);
                *(s4v*)(outb + (size_t)col * EMB + grow0) = o;
            }
        }
    } else if constexpr (EPI == 1 || EPI == 6) {
#pragma unroll
        for (int m = 0; m < 2; m++)
#pragma unroll
            for (int n = 0; n < 8; n++) {
                int col = colbase + n * 16 + lr;
#pragma unroll
                for (int r = 0; r < 4; r++) {
                    int grow = rowbase + m * 16 + kg * 4 + r;
                    float v = acc[m][n][r] + bcol[n];
                    if constexpr (EPI == 1) v = fmaxf(v, 0.f);
                    outb[(size_t)grow * EMB + col] = f2bf(v);
                }
            }
    } else {  // EPI 3: resid + LayerNorm -> f32
        float sm[2][4] = {}, sq2[2][4] = {};
#pragma unroll
        for (int m = 0; m < 2; m++)
#pragma unroll
            for (int n = 0; n < 8; n++) {
                int col = colbase + n * 16 + lr;
#pragma unroll
                for (int r = 0; r < 4; r++) {
                    int grow = rowbase + m * 16 + kg * 4 + r;
                    float v = acc[m][n][r] + bcol[n] + resid[(size_t)grow * EMB + col];
                    acc[m][n][r] = v;
                    sm[m][r] += v;
                    sq2[m][r] += v * v;
                }
            }
#pragma unroll
        for (int m = 0; m < 2; m++)
#pragma unroll
            for (int r = 0; r < 4; r++) {
                float s = sm[m][r], t = sq2[m][r];
                s += __shfl_xor(s, 1); t += __shfl_xor(t, 1);
                s += __shfl_xor(s, 2); t += __shfl_xor(t, 2);
                s += __shfl_xor(s, 4); t += __shfl_xor(t, 4);
                s += __shfl_xor(s, 8); t += __shfl_xor(t, 8);
                if (lr == 0) {
                    atomicAdd(&lsum[m * 16 + kg * 4 + r], s);
                    atomicAdd(&lsq[m * 16 + kg * 4 + r], t);
                }
            }
        __syncthreads();
#pragma unroll
        for (int m = 0; m < 2; m++)
#pragma unroll
            for (int r = 0; r < 4; r++) {
                int rowl = m * 16 + kg * 4 + r;
                int grow = rowbase + rowl;
                float mean = lsum[rowl] * (1.f / EMB);
                float var = lsq[rowl] * (1.f / EMB) - mean * mean;
                float rstd = rsqrtf(var + 1e-5f);
#pragma unroll
                for (int n = 0; n < 8; n++) {
                    int col = colbase + n * 16 + lr;
                    float yv = (acc[m][n][r] - mean) * rstd * gam[col] + bet[col];
                    outf[(size_t)grow * EMB + col] = yv;
                }
            }
    }
}

// ---------------- suffix-mean scan ----------------
// Phase 1: partial[b][c][e] = sum over 64 rows of chunk c of VO (bf16 in, f32 out)
__global__ __launch_bounds__(256) void scan_p1(const short* __restrict__ VO,
                                               float* __restrict__ partial) {
    __shared__ float wsum[4][EMB];
    int bid = blockIdx.x;
    int b = bid >> 5, c = bid & (NCH - 1);
    int g = threadIdx.x >> 6, lane = threadIdx.x & 63;
    int col8 = lane * 8;
    const short* base = VO + ((size_t)b * SEQ + c * 64 + g * 16) * EMB + col8;
    float acc[8] = {};
    for (int it = 0; it < 16; it++) {
        s8v v = *(const s8v*)(base + (size_t)it * EMB);
#pragma unroll
        for (int j = 0; j < 8; j++) acc[j] += bf2f(v[j]);
    }
#pragma unroll
    for (int j = 0; j < 8; j++) wsum[g][col8 + j] = acc[j];
    __syncthreads();
    if (g == 0) {
#pragma unroll
        for (int j = 0; j < 8; j++) {
            int e = col8 + j;
            partial[((size_t)b * NCH + c) * EMB + e] =
                wsum[0][e] + wsum[1][e] + wsum[2][e] + wsum[3][e];
        }
    }
}

// Phase 2: AO[i][e] = (sum_{j>i} VO[j][e]) / (SEQ-1-i)  (row SEQ-1: mean over all)
__global__ __launch_bounds__(256) void scan_p2(const short* __restrict__ VO,
                                               const float* __restrict__ partial,
                                               short* __restrict__ AO) {
    __shared__ float wsum[4][EMB];
    int bid = blockIdx.x;
    int b = bid >> 5, c = bid & (NCH - 1);
    int g = threadIdx.x >> 6, lane = threadIdx.x & 63;
    int col8 = lane * 8;

    // chunk-level offsets: off = sum over chunks > c; alltot = sum over all chunks
    float off[8] = {}, alltot[8] = {};
    for (int cc = 0; cc < NCH; cc++) {
        const float* pp = partial + ((size_t)b * NCH + cc) * EMB + col8;
#pragma unroll
        for (int j = 0; j < 8; j++) {
            float v = pp[j];
            alltot[j] += v;
            if (cc > c) off[j] += v;
        }
    }
    // wave-level partial sums within chunk (16 rows each)
    const short* base = VO + ((size_t)b * SEQ + c * 64 + g * 16) * EMB + col8;
    {
        float acc[8] = {};
        for (int it = 0; it < 16; it++) {
            s8v v = *(const s8v*)(base + (size_t)it * EMB);
#pragma unroll
            for (int j = 0; j < 8; j++) acc[j] += bf2f(v[j]);
        }
#pragma unroll
        for (int j = 0; j < 8; j++) wsum[g][col8 + j] = acc[j];
    }
    __syncthreads();
    float suf[8];
#pragma unroll
    for (int j = 0; j < 8; j++) {
        float s = off[j];
        for (int gg = g + 1; gg < 4; gg++) s += wsum[gg][col8 + j];
        suf[j] = s;
    }
    // bottom-up scan over this wave's 16 rows
    short* aobase = AO + ((size_t)b * SEQ + c * 64 + g * 16) * EMB + col8;
    for (int it = 15; it >= 0; it--) {
        int gi = c * 64 + g * 16 + it;
        s8v v = *(const s8v*)(base + (size_t)it * EMB);
        s8v o;
        if (gi == SEQ - 1) {
            float inv = 1.0f / (float)SEQ;
#pragma unroll
            for (int j = 0; j < 8; j++) o[j] = f2bf(alltot[j] * inv);
        } else {
            float inv = __builtin_amdgcn_rcpf((float)(SEQ - 1 - gi));
#pragma unroll
            for (int j = 0; j < 8; j++) o[j] = f2bf(suf[j] * inv);
        }
        *(s8v*)(aobase + (size_t)it * EMB) = o;
#pragma unroll
        for (int j = 0; j < 8; j++) suf[j] += bf2f(v[j]);
    }
}

// ---------------- LN1: x = LayerNorm(q + AO) -> X f32, Xbf bf16 ----------------
__global__ __launch_bounds__(256) void ln_kernel(
    const float* __restrict__ q, const short* __restrict__ AO,
    const float* __restrict__ gam, const float* __restrict__ bet,
    float* __restrict__ X, short* __restrict__ Xbf) {
    int w = threadIdx.x >> 6, lane = threadIdx.x & 63;
    int row0 = blockIdx.x * 32 + w * 8;
    for (int it = 0; it < 8; it++) {
        size_t grow = row0 + it;
        const float* qp = q + grow * EMB + lane * 8;
        float4 qa = *(const float4*)qp;
        float4 qb = *(const float4*)(qp + 4);
        s8v ao = *(const s8v*)(AO + grow * EMB + lane * 8);
        float v[8];
        v[0] = qa.x + bf2f(ao[0]); v[1] = qa.y + bf2f(ao[1]);
        v[2] = qa.z + bf2f(ao[2]); v[3] = qa.w + bf2f(ao[3]);
        v[4] = qb.x + bf2f(ao[4]); v[5] = qb.y + bf2f(ao[5]);
        v[6] = qb.z + bf2f(ao[6]); v[7] = qb.w + bf2f(ao[7]);
        float s = 0.f, t = 0.f;
#pragma unroll
        for (int j = 0; j < 8; j++) { s += v[j]; t += v[j] * v[j]; }
#pragma unroll
        for (int m = 32; m >= 1; m >>= 1) {
            s += __shfl_xor(s, m);
            t += __shfl_xor(t, m);
        }
        float mean = s * (1.f / EMB);
        float var = t * (1.f / EMB) - mean * mean;
        float rstd = rsqrtf(var + 1e-5f);
        float xo[8];
        s8v xb;
#pragma unroll
        for (int j = 0; j < 8; j++) {
            int col = lane * 8 + j;
            xo[j] = (v[j] - mean) * rstd * gam[col] + bet[col];
            xb[j] = f2bf(xo[j]);
        }
        float* xp = X + grow * EMB + lane * 8;
        *(float4*)xp = make_float4(xo[0], xo[1], xo[2], xo[3]);
        *(float4*)(xp + 4) = make_float4(xo[4], xo[5], xo[6], xo[7]);
        *(s8v*)(Xbf + grow * EMB + lane * 8) = xb;
    }
}

// ---------------- launch ----------------

extern "C" void kernel_launch(void* const* d_in, const int* in_sizes, int n_in,
                              void* d_out, int out_size, void* d_ws, size_t ws_size,
                              hipStream_t stream) {
    (void)in_sizes; (void)n_in; (void)out_size; (void)ws_size;
    const float* q     = (const float*)d_in[0];
    const float* k     = (const float*)d_in[1];
    const float* v_W   = (const float*)d_in[3];
    const float* v_b   = (const float*)d_in[4];
    const float* out_W = (const float*)d_in[5];
    const float* out_b = (const float*)d_in[6];
    const float* ln1_g = (const float*)d_in[7];
    const float* ln1_b = (const float*)d_in[8];
    const float* w1    = (const float*)d_in[9];
    const float* b1    = (const float*)d_in[10];
    const float* w2    = (const float*)d_in[11];
    const float* b2    = (const float*)d_in[12];
    const float* ln2_g = (const float*)d_in[13];
    const float* ln2_b = (const float*)d_in[14];

    char* ws = (char*)d_ws;
    const size_t MB = 1u << 20;
    short* KB   = (short*)(ws);            // 0-16MB bf16 k (dead after VO gemm)
    short* VO   = (short*)(ws + 16 * MB);  // 16-32MB bf16 k@Wc+bc (dead after scan)
    short* AO   = (short*)(ws + 32 * MB);  // 32-48MB bf16 attn_out (dead after ln)
    float* X    = (float*)(ws);            // 0-32MB f32 x (overlays KB+VO, both dead)
    short* H1   = (short*)(ws + 32 * MB);  // 32-48MB bf16 relu (overlays dead AO)
    short* Xbf  = (short*)(ws + 48 * MB);  // 48-64MB bf16 x
    short* VWb  = (short*)(ws + 64 * MB);  // v_W bf16 row-major
    short* WoT  = VWb + 512 * 512;         // out_W^T bf16
    short* W1T  = WoT + 512 * 512;
    short* W2T  = W1T + 512 * 512;
    short* WcT  = W2T + 512 * 512;         // (v_W@out_W)^T bf16
    float* bc   = (float*)(WcT + 512 * 512);
    float* part = bc + EMB;                // 8*32*512 f32 chunk partials

    // prep: casts + combined weight/bias
    cast8<<<BS * EMB / 8 / 256, 256, 0, stream>>>(k, KB, BS * EMB / 8);
    cast8<<<EMB * EMB / 8 / 256, 256, 0, stream>>>(v_W, VWb, EMB * EMB / 8);
    castWT<<<128, 256, 0, stream>>>(out_W, WoT);
    castWT<<<128, 256, 0, stream>>>(w1, W1T);
    castWT<<<128, 256, 0, stream>>>(w2, W2T);
    bias_combine<<<2, 256, 0, stream>>>(v_b, out_W, out_b, bc);

    // Wc^T = (v_W @ out_W)^T  (512x512, bf16)
    gemm512<5><<<EMB / 32, 256, 0, stream>>>(VWb, WoT, nullptr, nullptr, nullptr,
                                             WcT, nullptr, nullptr);
    // VO = k @ Wc + bc  (bf16 row-major)
    gemm512<6><<<BS / 32, 256, 0, stream>>>(KB, WcT, bc, nullptr, nullptr, VO,
                                            nullptr, nullptr);
    // attn_out via suffix-mean scan
    scan_p1<<<BATCH * NCH, 256, 0, stream>>>(VO, part);
    scan_p2<<<BATCH * NCH, 256, 0, stream>>>(VO, part, AO);
    // x = LN1(q + attn_out) -> X f32, Xbf bf16
    ln_kernel<<<BS / 32, 256, 0, stream>>>(q, AO, ln1_g, ln1_b, X, Xbf);
    // h1 = relu(x @ w1 + b1)
    gemm512<1><<<BS / 32, 256, 0, stream>>>(Xbf, W1T, b1, nullptr, nullptr, H1,
                                            nullptr, nullptr);
    // out = LN2(x + h1 @ w2 + b2)
    gemm512<3><<<BS / 32, 256, 0, stream>>>(H1, W2T, b2, X, (float*)d_out,
                                            nullptr, ln2_g, ln2_b);
}

// Round 4
// 135.260 us; speedup vs baseline: 5.8214x; 1.7618x over previous
//
#include <hip/hip_runtime.h>

typedef __attribute__((ext_vector_type(8))) short s8v;
typedef __attribute__((ext_vector_type(4))) short s4v;
typedef __attribute__((ext_vector_type(4))) float f4v;

constexpr int SEQ = 2048;
constexpr int EMB = 512;
constexpr int BATCH = 8;
constexpr int BS = BATCH * SEQ;  // 16384
constexpr int NCH = 32;          // scan chunks per batch (64 rows each)

#define DEVINL __device__ __forceinline__

DEVINL float bf2f(short s) {
    union { unsigned u; float f; } v;
    v.u = ((unsigned)(unsigned short)s) << 16;
    return v.f;
}
DEVINL short f2bf(float f) {
    union { float f; unsigned u; } v; v.f = f;
    unsigned u = v.u;
    return (short)((u + 0x7FFFu + ((u >> 16) & 1u)) >> 16);
}
DEVINL f4v mfma16(s8v a, s8v b, f4v c) {
    return __builtin_amdgcn_mfma_f32_16x16x32_bf16(a, b, c, 0, 0, 0);
}
DEVINL s8v pack8(float4 a, float4 b) {
    s8v o;
    o[0] = f2bf(a.x); o[1] = f2bf(a.y); o[2] = f2bf(a.z); o[3] = f2bf(a.w);
    o[4] = f2bf(b.x); o[5] = f2bf(b.y); o[6] = f2bf(b.z); o[7] = f2bf(b.w);
    return o;
}
DEVINL void gload16(const short* g, short* l) {
    __builtin_amdgcn_global_load_lds(
        (const __attribute__((address_space(1))) void*)g,
        (__attribute__((address_space(3))) void*)l, 16, 0, 0);
}

// ---------------- combined prep kernel ----------------
// blocks [0,384): castWT of out_W/w1/w2 -> WoT/W1T/W2T  (WT[n][k] = W[k][n])
// blocks [384,512): cast v_W row-major -> VWb
// blocks [512,514): bc[n] = sum_m v_b[m]*out_W[m][n] + out_b[n]
__global__ __launch_bounds__(256) void prep_all(
    const float* __restrict__ out_W, const float* __restrict__ w1,
    const float* __restrict__ w2, const float* __restrict__ v_W,
    const float* __restrict__ v_b, const float* __restrict__ out_b,
    short* __restrict__ WoT, short* __restrict__ W1T, short* __restrict__ W2T,
    short* __restrict__ VWb, float* __restrict__ bc) {
    int blk = blockIdx.x;
    if (blk < 384) {
        const float* W = (blk < 128) ? out_W : (blk < 256 ? w1 : w2);
        short* WT = (blk < 128) ? WoT : (blk < 256 ? W1T : W2T);
        int t = (blk & 127) * 256 + threadIdx.x;
        int n = t >> 6;
        int k0 = (t & 63) * 8;
        s8v o;
#pragma unroll
        for (int e = 0; e < 8; e++) o[e] = f2bf(W[(size_t)(k0 + e) * EMB + n]);
        *(s8v*)(WT + (size_t)n * EMB + k0) = o;
    } else if (blk < 512) {
        int i = (blk - 384) * 256 + threadIdx.x;  // 32768 = 512*512/8
        const float* p = v_W + (size_t)i * 8;
        float4 a = *(const float4*)p;
        float4 b = *(const float4*)(p + 4);
        *(s8v*)(VWb + (size_t)i * 8) = pack8(a, b);
    } else {
        int n = (blk - 512) * 256 + threadIdx.x;
        float acc = 0.f;
        for (int m = 0; m < EMB; m++) acc += v_b[m] * out_W[(size_t)m * EMB + n];
        bc[n] = acc + out_b[n];
    }
}

// ---------------- small flat GEMM for Wc = v_W @ out_W (512x512) ----------------
// C[d][n] = sum_m A[d][m] * WT[n][m]; stores transposed: out[n][d]
__global__ __launch_bounds__(256) void wc_gemm(
    const short* __restrict__ A, const short* __restrict__ WT,
    short* __restrict__ outT) {
    const int tid = threadIdx.x;
    const int wave = tid >> 6, lane = tid & 63;
    const int lr = lane & 15, kg = lane >> 4;
    const int rowbase = blockIdx.x * 32;
    const int colbase = wave * 128;
    f4v acc[2][8] = {};
    const short* Ap0 = A + (size_t)(rowbase + lr) * EMB + kg * 8;
    const short* Ap1 = Ap0 + 16 * EMB;
    const short* Bp  = WT + (size_t)(colbase + lr) * EMB + kg * 8;
    for (int kk = 0; kk < EMB; kk += 32) {
        s8v a0 = *(const s8v*)(Ap0 + kk);
        s8v a1 = *(const s8v*)(Ap1 + kk);
#pragma unroll
        for (int n = 0; n < 8; n++) {
            s8v bv = *(const s8v*)(Bp + (size_t)n * 16 * EMB + kk);
            acc[0][n] = mfma16(a0, bv, acc[0][n]);
            acc[1][n] = mfma16(a1, bv, acc[1][n]);
        }
    }
#pragma unroll
    for (int m = 0; m < 2; m++) {
        int grow0 = rowbase + m * 16 + kg * 4;
#pragma unroll
        for (int n = 0; n < 8; n++) {
            int col = colbase + n * 16 + lr;
            s4v o;
#pragma unroll
            for (int r = 0; r < 4; r++) o[r] = f2bf(acc[m][n][r]);
            *(s4v*)(outT + (size_t)col * EMB + grow0) = o;
        }
    }
}

// ---------------- m97-style 128x128 tiled GEMM, K=512 ----------------
// C[M x 512] = A[M x 512] @ WT^T + bias. WT[n][k] row-major.
// grid = (M/128)*4, 256 threads (4 waves, 2x2), LDS double-buffered,
// global_load_lds staging with XOR-swizzled source, XCD-chunked block swizzle.
// EPI 0: +bias -> bf16 ; EPI 1: +bias, relu -> bf16
template <int EPI>
__global__ __launch_bounds__(256, 2) void mgemm(
    const short* __restrict__ A, const short* __restrict__ B,
    const float* __restrict__ bias, short* __restrict__ C) {
    __shared__ __attribute__((aligned(16))) short lds[2][16384];  // 64KB

    const int nwg = gridDim.x;
    const int q = nwg >> 3;
    const int bid = blockIdx.x;
    const int wg = (bid & 7) * q + (bid >> 3);  // bijective (nwg % 8 == 0)
    const int mt = wg >> 2, nt = wg & 3;
    const int mbase = mt * 128, nbase = nt * 128;

    const int tid = threadIdx.x;
    const int w = tid >> 6, lane = tid & 63;
    const int lr = lane & 15, kg = lane >> 4;
    const int wr = w >> 1, wc = w & 1;

    // per-lane staging sources (4 A insts + 4 B insts), swizzled column unit
    const short* gA[4];
    const short* gB[4];
    short* lA[4];
    short* lB[4];
#pragma unroll
    for (int inst = 0; inst < 4; inst++) {
        int U = inst * 256 + w * 64 + lane;  // 16B unit index, 0..1023
        int row = U >> 3, cu = U & 7;
        int csrc = cu ^ (row & 7);
        gA[inst] = A + (size_t)(mbase + row) * EMB + csrc * 8;
        gB[inst] = B + (size_t)(nbase + row) * EMB + csrc * 8;
        lA[inst] = &lds[0][(inst * 256 + w * 64) * 8];
        lB[inst] = &lds[0][8192 + (inst * 256 + w * 64) * 8];
    }

    // frag LDS short-offsets (within a buffer)
    int aoff[4][2], boff[4][2];
#pragma unroll
    for (int m = 0; m < 4; m++)
#pragma unroll
        for (int ks = 0; ks < 2; ks++) {
            int row = wr * 64 + m * 16 + lr;
            int cu = (ks * 4 + kg) ^ (row & 7);
            aoff[m][ks] = row * 64 + cu * 8;
        }
#pragma unroll
    for (int n = 0; n < 4; n++)
#pragma unroll
        for (int ks = 0; ks < 2; ks++) {
            int row = wc * 64 + n * 16 + lr;
            int cu = (ks * 4 + kg) ^ (row & 7);
            boff[n][ks] = 8192 + row * 64 + cu * 8;
        }

    auto stage = [&](int kt, int d) {
        int koff = kt * 64;  // shorts
        int dd = d * 16384;
#pragma unroll
        for (int inst = 0; inst < 4; inst++)
            gload16(gA[inst] + koff, lA[inst] + dd);
#pragma unroll
        for (int inst = 0; inst < 4; inst++)
            gload16(gB[inst] + koff, lB[inst] + dd);
    };

    f4v acc[4][4] = {};
    stage(0, 0);
    int cur = 0;
    for (int kt = 0; kt < 8; kt++) {
        __syncthreads();  // drains vmcnt: buf[cur] staged & visible
        if (kt < 7) stage(kt + 1, cur ^ 1);
        const short* base = &lds[cur][0];
        s8v afr[4][2], bfr[4][2];
#pragma unroll
        for (int m = 0; m < 4; m++)
#pragma unroll
            for (int ks = 0; ks < 2; ks++)
                afr[m][ks] = *(const s8v*)(base + aoff[m][ks]);
#pragma unroll
        for (int n = 0; n < 4; n++)
#pragma unroll
            for (int ks = 0; ks < 2; ks++)
                bfr[n][ks] = *(const s8v*)(base + boff[n][ks]);
#pragma unroll
        for (int ks = 0; ks < 2; ks++)
#pragma unroll
            for (int m = 0; m < 4; m++)
#pragma unroll
                for (int n = 0; n < 4; n++)
                    acc[m][n] = mfma16(afr[m][ks], bfr[n][ks], acc[m][n]);
        cur ^= 1;
    }

    float bcol[4];
#pragma unroll
    for (int n = 0; n < 4; n++) bcol[n] = bias[nbase + wc * 64 + n * 16 + lr];
#pragma unroll
    for (int m = 0; m < 4; m++)
#pragma unroll
        for (int n = 0; n < 4; n++) {
            int col = nbase + wc * 64 + n * 16 + lr;
#pragma unroll
            for (int r = 0; r < 4; r++) {
                int row = mbase + wr * 64 + m * 16 + kg * 4 + r;
                float v = acc[m][n][r] + bcol[n];
                if constexpr (EPI == 1) v = fmaxf(v, 0.f);
                C[(size_t)row * EMB + col] = f2bf(v);
            }
        }
}

// ---------------- suffix-mean scan over k (f32 in, bf16 mean out) ----------------
// Phase 1: partial[b][c][e] = sum over 64 rows of chunk c of k
__global__ __launch_bounds__(256) void scan_p1(const float* __restrict__ K,
                                               float* __restrict__ partial) {
    __shared__ float wsum[4][EMB];
    int b = blockIdx.x >> 5, c = blockIdx.x & (NCH - 1);
    int g = threadIdx.x >> 6, lane = threadIdx.x & 63;
    int col8 = lane * 8;
    const float* base = K + ((size_t)b * SEQ + c * 64 + g * 16) * EMB + col8;
    float acc[8] = {};
    for (int it = 0; it < 16; it++) {
        float4 a = *(const float4*)(base + (size_t)it * EMB);
        float4 bb = *(const float4*)(base + (size_t)it * EMB + 4);
        acc[0] += a.x; acc[1] += a.y; acc[2] += a.z; acc[3] += a.w;
        acc[4] += bb.x; acc[5] += bb.y; acc[6] += bb.z; acc[7] += bb.w;
    }
#pragma unroll
    for (int j = 0; j < 8; j++) wsum[g][col8 + j] = acc[j];
    __syncthreads();
    if (g == 0) {
#pragma unroll
        for (int j = 0; j < 8; j++) {
            int e = col8 + j;
            partial[((size_t)b * NCH + c) * EMB + e] =
                wsum[0][e] + wsum[1][e] + wsum[2][e] + wsum[3][e];
        }
    }
}

// Phase 2: SK[i][e] = (sum_{j>i} k[j][e]) / (SEQ-1-i)   (row SEQ-1: mean over all)
__global__ __launch_bounds__(256) void scan_p2(const float* __restrict__ K,
                                               const float* __restrict__ partial,
                                               short* __restrict__ SK) {
    __shared__ float wsum[4][EMB];
    int b = blockIdx.x >> 5, c = blockIdx.x & (NCH - 1);
    int g = threadIdx.x >> 6, lane = threadIdx.x & 63;
    int col8 = lane * 8;

    float off[8] = {}, alltot[8] = {};
    for (int cc = 0; cc < NCH; cc++) {
        const float* pp = partial + ((size_t)b * NCH + cc) * EMB + col8;
        float4 pa = *(const float4*)pp;
        float4 pb = *(const float4*)(pp + 4);
        float v[8] = {pa.x, pa.y, pa.z, pa.w, pb.x, pb.y, pb.z, pb.w};
#pragma unroll
        for (int j = 0; j < 8; j++) {
            alltot[j] += v[j];
            if (cc > c) off[j] += v[j];
        }
    }
    const float* base = K + ((size_t)b * SEQ + c * 64 + g * 16) * EMB + col8;
    {
        float acc[8] = {};
        for (int it = 0; it < 16; it++) {
            float4 a = *(const float4*)(base + (size_t)it * EMB);
            float4 bb = *(const float4*)(base + (size_t)it * EMB + 4);
            acc[0] += a.x; acc[1] += a.y; acc[2] += a.z; acc[3] += a.w;
            acc[4] += bb.x; acc[5] += bb.y; acc[6] += bb.z; acc[7] += bb.w;
        }
#pragma unroll
        for (int j = 0; j < 8; j++) wsum[g][col8 + j] = acc[j];
    }
    __syncthreads();
    float suf[8];
#pragma unroll
    for (int j = 0; j < 8; j++) {
        float s = off[j];
        for (int gg = g + 1; gg < 4; gg++) s += wsum[gg][col8 + j];
        suf[j] = s;
    }
    short* skbase = SK + ((size_t)b * SEQ + c * 64 + g * 16) * EMB + col8;
    for (int it = 15; it >= 0; it--) {
        int gi = c * 64 + g * 16 + it;
        float4 a = *(const float4*)(base + (size_t)it * EMB);
        float4 bb = *(const float4*)(base + (size_t)it * EMB + 4);
        s8v o;
        if (gi == SEQ - 1) {
            float inv = 1.0f / (float)SEQ;
#pragma unroll
            for (int j = 0; j < 8; j++) o[j] = f2bf(alltot[j] * inv);
        } else {
            float inv = __builtin_amdgcn_rcpf((float)(SEQ - 1 - gi));
#pragma unroll
            for (int j = 0; j < 8; j++) o[j] = f2bf(suf[j] * inv);
        }
        *(s8v*)(skbase + (size_t)it * EMB) = o;
        suf[0] += a.x; suf[1] += a.y; suf[2] += a.z; suf[3] += a.w;
        suf[4] += bb.x; suf[5] += bb.y; suf[6] += bb.z; suf[7] += bb.w;
    }
}

// ---------------- LN1: Xbf = LayerNorm(q + VO2) (bf16 out) ----------------
__global__ __launch_bounds__(256) void ln1_kernel(
    const float* __restrict__ q, const short* __restrict__ VO2,
    const float* __restrict__ gam, const float* __restrict__ bet,
    short* __restrict__ Xbf) {
    int w = threadIdx.x >> 6, lane = threadIdx.x & 63;
    int row0 = blockIdx.x * 32 + w * 8;
    for (int it = 0; it < 8; it++) {
        size_t grow = row0 + it;
        const float* qp = q + grow * EMB + lane * 8;
        float4 qa = *(const float4*)qp;
        float4 qb = *(const float4*)(qp + 4);
        s8v ao = *(const s8v*)(VO2 + grow * EMB + lane * 8);
        float v[8];
        v[0] = qa.x + bf2f(ao[0]); v[1] = qa.y + bf2f(ao[1]);
        v[2] = qa.z + bf2f(ao[2]); v[3] = qa.w + bf2f(ao[3]);
        v[4] = qb.x + bf2f(ao[4]); v[5] = qb.y + bf2f(ao[5]);
        v[6] = qb.z + bf2f(ao[6]); v[7] = qb.w + bf2f(ao[7]);
        float s = 0.f, t = 0.f;
#pragma unroll
        for (int j = 0; j < 8; j++) { s += v[j]; t += v[j] * v[j]; }
#pragma unroll
        for (int m = 32; m >= 1; m >>= 1) {
            s += __shfl_xor(s, m);
            t += __shfl_xor(t, m);
        }
        float mean = s * (1.f / EMB);
        float var = t * (1.f / EMB) - mean * mean;
        float rstd = rsqrtf(var + 1e-5f);
        s8v xb;
#pragma unroll
        for (int j = 0; j < 8; j++) {
            int col = lane * 8 + j;
            xb[j] = f2bf((v[j] - mean) * rstd * gam[col] + bet[col]);
        }
        *(s8v*)(Xbf + grow * EMB + lane * 8) = xb;
    }
}

// ---------------- LN2: out = LayerNorm(Xbf + Y) (f32 out) ----------------
__global__ __launch_bounds__(256) void ln2_kernel(
    const short* __restrict__ Xbf, const short* __restrict__ Y,
    const float* __restrict__ gam, const float* __restrict__ bet,
    float* __restrict__ out) {
    int w = threadIdx.x >> 6, lane = threadIdx.x & 63;
    int row0 = blockIdx.x * 32 + w * 8;
    for (int it = 0; it < 8; it++) {
        size_t grow = row0 + it;
        s8v xv = *(const s8v*)(Xbf + grow * EMB + lane * 8);
        s8v yv = *(const s8v*)(Y + grow * EMB + lane * 8);
        float v[8];
#pragma unroll
        for (int j = 0; j < 8; j++) v[j] = bf2f(xv[j]) + bf2f(yv[j]);
        float s = 0.f, t = 0.f;
#pragma unroll
        for (int j = 0; j < 8; j++) { s += v[j]; t += v[j] * v[j]; }
#pragma unroll
        for (int m = 32; m >= 1; m >>= 1) {
            s += __shfl_xor(s, m);
            t += __shfl_xor(t, m);
        }
        float mean = s * (1.f / EMB);
        float var = t * (1.f / EMB) - mean * mean;
        float rstd = rsqrtf(var + 1e-5f);
        float xo[8];
#pragma unroll
        for (int j = 0; j < 8; j++) {
            int col = lane * 8 + j;
            xo[j] = (v[j] - mean) * rstd * gam[col] + bet[col];
        }
        float* op = out + grow * EMB + lane * 8;
        *(float4*)op = make_float4(xo[0], xo[1], xo[2], xo[3]);
        *(float4*)(op + 4) = make_float4(xo[4], xo[5], xo[6], xo[7]);
    }
}

// ---------------- launch ----------------

extern "C" void kernel_launch(void* const* d_in, const int* in_sizes, int n_in,
                              void* d_out, int out_size, void* d_ws, size_t ws_size,
                              hipStream_t stream) {
    (void)in_sizes; (void)n_in; (void)out_size; (void)ws_size;
    const float* q     = (const float*)d_in[0];
    const float* k     = (const float*)d_in[1];
    const float* v_W   = (const float*)d_in[3];
    const float* v_b   = (const float*)d_in[4];
    const float* out_W = (const float*)d_in[5];
    const float* out_b = (const float*)d_in[6];
    const float* ln1_g = (const float*)d_in[7];
    const float* ln1_b = (const float*)d_in[8];
    const float* w1    = (const float*)d_in[9];
    const float* b1    = (const float*)d_in[10];
    const float* w2    = (const float*)d_in[11];
    const float* b2    = (const float*)d_in[12];
    const float* ln2_g = (const float*)d_in[13];
    const float* ln2_b = (const float*)d_in[14];

    char* ws = (char*)d_ws;
    const size_t MB = 1u << 20;
    short* SK   = (short*)(ws);            // 16MB bf16 suffix-mean of k
    short* VO2  = (short*)(ws + 16 * MB);  // 16MB bf16 SK@Wc + bc
    short* Xbf  = (short*)(ws + 32 * MB);  // 16MB bf16 x (post-LN1)
    short* H1   = (short*)(ws + 48 * MB);  // 16MB bf16 relu(x@w1+b1)
    short* Y    = (short*)(ws + 64 * MB);  // 16MB bf16 h1@w2+b2
    short* WoT  = (short*)(ws + 80 * MB);  // out_W^T bf16
    short* W1T  = WoT + 512 * 512;
    short* W2T  = W1T + 512 * 512;
    short* VWb  = W2T + 512 * 512;         // v_W bf16 row-major
    short* WcT  = VWb + 512 * 512;         // (v_W@out_W)^T bf16
    float* bc   = (float*)(WcT + 512 * 512);
    float* part = bc + EMB;                // 8*32*512 f32 chunk partials

    prep_all<<<514, 256, 0, stream>>>(out_W, w1, w2, v_W, v_b, out_b,
                                      WoT, W1T, W2T, VWb, bc);
    // Wc^T = (v_W @ out_W)^T
    wc_gemm<<<EMB / 32, 256, 0, stream>>>(VWb, WoT, WcT);
    // suffix-mean of k
    scan_p1<<<BATCH * NCH, 256, 0, stream>>>(k, part);
    scan_p2<<<BATCH * NCH, 256, 0, stream>>>(k, part, SK);
    // attn_out = SK @ Wc + bc
    mgemm<0><<<(BS / 128) * 4, 256, 0, stream>>>(SK, WcT, bc, VO2);
    // x = LN1(q + attn_out)
    ln1_kernel<<<BS / 32, 256, 0, stream>>>(q, VO2, ln1_g, ln1_b, Xbf);
    // h1 = relu(x @ w1 + b1)
    mgemm<1><<<(BS / 128) * 4, 256, 0, stream>>>(Xbf, W1T, b1, H1);
    // y = h1 @ w2 + b2
    mgemm<0><<<(BS / 128) * 4, 256, 0, stream>>>(H1, W2T, b2, Y);
    // out = LN2(x + y)
    ln2_kernel<<<BS / 32, 256, 0, stream>>>(Xbf, Y, ln2_g, ln2_b, (float*)d_out);
}

// Round 5
// 114.593 us; speedup vs baseline: 6.8712x; 1.1803x over previous
//
#include <hip/hip_runtime.h>

typedef __attribute__((ext_vector_type(8))) short s8v;
typedef __attribute__((ext_vector_type(4))) float f4v;

constexpr int SEQ = 2048;
constexpr int EMB = 512;
constexpr int BATCH = 8;
constexpr int BS = BATCH * SEQ;  // 16384
constexpr int NCH = 32;          // scan chunks per batch (64 rows each)

#define DEVINL __device__ __forceinline__

DEVINL float bf2f(short s) {
    union { unsigned u; float f; } v;
    v.u = ((unsigned)(unsigned short)s) << 16;
    return v.f;
}
DEVINL short f2bf(float f) {
    union { float f; unsigned u; } v; v.f = f;
    unsigned u = v.u;
    return (short)((u + 0x7FFFu + ((u >> 16) & 1u)) >> 16);
}
DEVINL f4v mfma16(s8v a, s8v b, f4v c) {
    return __builtin_amdgcn_mfma_f32_16x16x32_bf16(a, b, c, 0, 0, 0);
}
DEVINL void gload16(const short* g, short* l) {
    __builtin_amdgcn_global_load_lds(
        (const __attribute__((address_space(1))) void*)g,
        (__attribute__((address_space(3))) void*)l, 16, 0, 0);
}

// ---------------- prep: 4x castWT (W [k][n] f32 -> WT [n][k] bf16) ----------------
__global__ __launch_bounds__(256) void prep_all(
    const float* __restrict__ v_W, const float* __restrict__ out_W,
    const float* __restrict__ w1, const float* __restrict__ w2,
    short* __restrict__ VvT, short* __restrict__ WoT,
    short* __restrict__ W1T, short* __restrict__ W2T) {
    int blk = blockIdx.x;  // 512 blocks: 128 per weight
    const float* W;
    short* WT;
    if (blk < 128)      { W = v_W;   WT = VvT; }
    else if (blk < 256) { W = out_W; WT = WoT; }
    else if (blk < 384) { W = w1;    WT = W1T; }
    else                { W = w2;    WT = W2T; }
    int t = (blk & 127) * 256 + threadIdx.x;
    int n = t >> 6;
    int k0 = (t & 63) * 8;
    s8v o;
#pragma unroll
    for (int e = 0; e < 8; e++) o[e] = f2bf(W[(size_t)(k0 + e) * EMB + n]);
    *(s8v*)(WT + (size_t)n * EMB + k0) = o;
}

// ---------------- m97-style 128x128 tiled GEMM, K=512 ----------------
// C[M x 512] = A[M x 512] @ WT^T + bias. WT[n][k] row-major.
// grid = (M/128)*4, 256 threads (4 waves, 2x2), LDS double-buffered,
// global_load_lds staging with XOR-swizzled source, XCD-chunked block swizzle.
// EPI 0: +bias -> bf16 ; EPI 1: +bias, relu -> bf16
template <int EPI>
__global__ __launch_bounds__(256, 2) void mgemm(
    const short* __restrict__ A, const short* __restrict__ B,
    const float* __restrict__ bias, short* __restrict__ C) {
    __shared__ __attribute__((aligned(16))) short lds[2][16384];  // 64KB

    const int nwg = gridDim.x;
    const int q = nwg >> 3;
    const int bid = blockIdx.x;
    const int wg = (bid & 7) * q + (bid >> 3);  // bijective (nwg % 8 == 0)
    const int mt = wg >> 2, nt = wg & 3;
    const int mbase = mt * 128, nbase = nt * 128;

    const int tid = threadIdx.x;
    const int w = tid >> 6, lane = tid & 63;
    const int lr = lane & 15, kg = lane >> 4;
    const int wr = w >> 1, wc = w & 1;

    // per-lane staging sources (4 A insts + 4 B insts), swizzled column unit
    const short* gA[4];
    const short* gB[4];
    short* lA[4];
    short* lB[4];
#pragma unroll
    for (int inst = 0; inst < 4; inst++) {
        int U = inst * 256 + w * 64 + lane;  // 16B unit index, 0..1023
        int row = U >> 3, cu = U & 7;
        int csrc = cu ^ (row & 7);
        gA[inst] = A + (size_t)(mbase + row) * EMB + csrc * 8;
        gB[inst] = B + (size_t)(nbase + row) * EMB + csrc * 8;
        lA[inst] = &lds[0][(inst * 256 + w * 64) * 8];
        lB[inst] = &lds[0][8192 + (inst * 256 + w * 64) * 8];
    }

    // frag LDS short-offsets (within a buffer)
    int aoff[4][2], boff[4][2];
#pragma unroll
    for (int m = 0; m < 4; m++)
#pragma unroll
        for (int ks = 0; ks < 2; ks++) {
            int row = wr * 64 + m * 16 + lr;
            int cu = (ks * 4 + kg) ^ (row & 7);
            aoff[m][ks] = row * 64 + cu * 8;
        }
#pragma unroll
    for (int n = 0; n < 4; n++)
#pragma unroll
        for (int ks = 0; ks < 2; ks++) {
            int row = wc * 64 + n * 16 + lr;
            int cu = (ks * 4 + kg) ^ (row & 7);
            boff[n][ks] = 8192 + row * 64 + cu * 8;
        }

    auto stage = [&](int kt, int d) {
        int koff = kt * 64;  // shorts
        int dd = d * 16384;
#pragma unroll
        for (int inst = 0; inst < 4; inst++)
            gload16(gA[inst] + koff, lA[inst] + dd);
#pragma unroll
        for (int inst = 0; inst < 4; inst++)
            gload16(gB[inst] + koff, lB[inst] + dd);
    };

    f4v acc[4][4] = {};
    stage(0, 0);
    int cur = 0;
    for (int kt = 0; kt < 8; kt++) {
        __syncthreads();  // drains vmcnt: buf[cur] staged & visible
        if (kt < 7) stage(kt + 1, cur ^ 1);
        const short* base = &lds[cur][0];
        s8v afr[4][2], bfr[4][2];
#pragma unroll
        for (int m = 0; m < 4; m++)
#pragma unroll
            for (int ks = 0; ks < 2; ks++)
                afr[m][ks] = *(const s8v*)(base + aoff[m][ks]);
#pragma unroll
        for (int n = 0; n < 4; n++)
#pragma unroll
            for (int ks = 0; ks < 2; ks++)
                bfr[n][ks] = *(const s8v*)(base + boff[n][ks]);
#pragma unroll
        for (int ks = 0; ks < 2; ks++)
#pragma unroll
            for (int m = 0; m < 4; m++)
#pragma unroll
                for (int n = 0; n < 4; n++)
                    acc[m][n] = mfma16(afr[m][ks], bfr[n][ks], acc[m][n]);
        cur ^= 1;
    }

    float bcol[4];
#pragma unroll
    for (int n = 0; n < 4; n++) bcol[n] = bias[nbase + wc * 64 + n * 16 + lr];
#pragma unroll
    for (int m = 0; m < 4; m++)
#pragma unroll
        for (int n = 0; n < 4; n++) {
            int col = nbase + wc * 64 + n * 16 + lr;
#pragma unroll
            for (int r = 0; r < 4; r++) {
                int row = mbase + wr * 64 + m * 16 + kg * 4 + r;
                float v = acc[m][n][r] + bcol[n];
                if constexpr (EPI == 1) v = fmaxf(v, 0.f);
                C[(size_t)row * EMB + col] = f2bf(v);
            }
        }
}

// ---------------- suffix-mean scan over k (f32 in, bf16 mean out) ----------------
// Phase 1: partial[b][c][e] = sum over 64 rows of chunk c of k
__global__ __launch_bounds__(256) void scan_p1(const float* __restrict__ K,
                                               float* __restrict__ partial) {
    __shared__ float wsum[4][EMB];
    int b = blockIdx.x >> 5, c = blockIdx.x & (NCH - 1);
    int g = threadIdx.x >> 6, lane = threadIdx.x & 63;
    int col8 = lane * 8;
    const float* base = K + ((size_t)b * SEQ + c * 64 + g * 16) * EMB + col8;
    float acc[8] = {};
    for (int it = 0; it < 16; it++) {
        float4 a = *(const float4*)(base + (size_t)it * EMB);
        float4 bb = *(const float4*)(base + (size_t)it * EMB + 4);
        acc[0] += a.x; acc[1] += a.y; acc[2] += a.z; acc[3] += a.w;
        acc[4] += bb.x; acc[5] += bb.y; acc[6] += bb.z; acc[7] += bb.w;
    }
#pragma unroll
    for (int j = 0; j < 8; j++) wsum[g][col8 + j] = acc[j];
    __syncthreads();
    if (g == 0) {
#pragma unroll
        for (int j = 0; j < 8; j++) {
            int e = col8 + j;
            partial[((size_t)b * NCH + c) * EMB + e] =
                wsum[0][e] + wsum[1][e] + wsum[2][e] + wsum[3][e];
        }
    }
}

// Phase 2: SK[i][e] = (sum_{j>i} k[j][e]) / (SEQ-1-i)   (row SEQ-1: mean over all)
__global__ __launch_bounds__(256) void scan_p2(const float* __restrict__ K,
                                               const float* __restrict__ partial,
                                               short* __restrict__ SK) {
    __shared__ float wsum[4][EMB];
    int b = blockIdx.x >> 5, c = blockIdx.x & (NCH - 1);
    int g = threadIdx.x >> 6, lane = threadIdx.x & 63;
    int col8 = lane * 8;

    float off[8] = {}, alltot[8] = {};
    for (int cc = 0; cc < NCH; cc++) {
        const float* pp = partial + ((size_t)b * NCH + cc) * EMB + col8;
        float4 pa = *(const float4*)pp;
        float4 pb = *(const float4*)(pp + 4);
        float v[8] = {pa.x, pa.y, pa.z, pa.w, pb.x, pb.y, pb.z, pb.w};
#pragma unroll
        for (int j = 0; j < 8; j++) {
            alltot[j] += v[j];
            if (cc > c) off[j] += v[j];
        }
    }
    const float* base = K + ((size_t)b * SEQ + c * 64 + g * 16) * EMB + col8;
    {
        float acc[8] = {};
        for (int it = 0; it < 16; it++) {
            float4 a = *(const float4*)(base + (size_t)it * EMB);
            float4 bb = *(const float4*)(base + (size_t)it * EMB + 4);
            acc[0] += a.x; acc[1] += a.y; acc[2] += a.z; acc[3] += a.w;
            acc[4] += bb.x; acc[5] += bb.y; acc[6] += bb.z; acc[7] += bb.w;
        }
#pragma unroll
        for (int j = 0; j < 8; j++) wsum[g][col8 + j] = acc[j];
    }
    __syncthreads();
    float suf[8];
#pragma unroll
    for (int j = 0; j < 8; j++) {
        float s = off[j];
        for (int gg = g + 1; gg < 4; gg++) s += wsum[gg][col8 + j];
        suf[j] = s;
    }
    short* skbase = SK + ((size_t)b * SEQ + c * 64 + g * 16) * EMB + col8;
    for (int it = 15; it >= 0; it--) {
        int gi = c * 64 + g * 16 + it;
        float4 a = *(const float4*)(base + (size_t)it * EMB);
        float4 bb = *(const float4*)(base + (size_t)it * EMB + 4);
        s8v o;
        if (gi == SEQ - 1) {
            float inv = 1.0f / (float)SEQ;
#pragma unroll
            for (int j = 0; j < 8; j++) o[j] = f2bf(alltot[j] * inv);
        } else {
            float inv = __builtin_amdgcn_rcpf((float)(SEQ - 1 - gi));
#pragma unroll
            for (int j = 0; j < 8; j++) o[j] = f2bf(suf[j] * inv);
        }
        *(s8v*)(skbase + (size_t)it * EMB) = o;
        suf[0] += a.x; suf[1] += a.y; suf[2] += a.z; suf[3] += a.w;
        suf[4] += bb.x; suf[5] += bb.y; suf[6] += bb.z; suf[7] += bb.w;
    }
}

// ---------------- LN1: Xbf = LayerNorm(q + VO2) (bf16 out) ----------------
__global__ __launch_bounds__(256) void ln1_kernel(
    const float* __restrict__ q, const short* __restrict__ VO2,
    const float* __restrict__ gam, const float* __restrict__ bet,
    short* __restrict__ Xbf) {
    int w = threadIdx.x >> 6, lane = threadIdx.x & 63;
    int row0 = blockIdx.x * 32 + w * 8;
    for (int it = 0; it < 8; it++) {
        size_t grow = row0 + it;
        const float* qp = q + grow * EMB + lane * 8;
        float4 qa = *(const float4*)qp;
        float4 qb = *(const float4*)(qp + 4);
        s8v ao = *(const s8v*)(VO2 + grow * EMB + lane * 8);
        float v[8];
        v[0] = qa.x + bf2f(ao[0]); v[1] = qa.y + bf2f(ao[1]);
        v[2] = qa.z + bf2f(ao[2]); v[3] = qa.w + bf2f(ao[3]);
        v[4] = qb.x + bf2f(ao[4]); v[5] = qb.y + bf2f(ao[5]);
        v[6] = qb.z + bf2f(ao[6]); v[7] = qb.w + bf2f(ao[7]);
        float s = 0.f, t = 0.f;
#pragma unroll
        for (int j = 0; j < 8; j++) { s += v[j]; t += v[j] * v[j]; }
#pragma unroll
        for (int m = 32; m >= 1; m >>= 1) {
            s += __shfl_xor(s, m);
            t += __shfl_xor(t, m);
        }
        float mean = s * (1.f / EMB);
        float var = t * (1.f / EMB) - mean * mean;
        float rstd = rsqrtf(var + 1e-5f);
        s8v xb;
#pragma unroll
        for (int j = 0; j < 8; j++) {
            int col = lane * 8 + j;
            xb[j] = f2bf((v[j] - mean) * rstd * gam[col] + bet[col]);
        }
        *(s8v*)(Xbf + grow * EMB + lane * 8) = xb;
    }
}

// ---------------- LN2: out = LayerNorm(Xbf + Y) (f32 out) ----------------
__global__ __launch_bounds__(256) void ln2_kernel(
    const short* __restrict__ Xbf, const short* __restrict__ Y,
    const float* __restrict__ gam, const float* __restrict__ bet,
    float* __restrict__ out) {
    int w = threadIdx.x >> 6, lane = threadIdx.x & 63;
    int row0 = blockIdx.x * 32 + w * 8;
    for (int it = 0; it < 8; it++) {
        size_t grow = row0 + it;
        s8v xv = *(const s8v*)(Xbf + grow * EMB + lane * 8);
        s8v yv = *(const s8v*)(Y + grow * EMB + lane * 8);
        float v[8];
#pragma unroll
        for (int j = 0; j < 8; j++) v[j] = bf2f(xv[j]) + bf2f(yv[j]);
        float s = 0.f, t = 0.f;
#pragma unroll
        for (int j = 0; j < 8; j++) { s += v[j]; t += v[j] * v[j]; }
#pragma unroll
        for (int m = 32; m >= 1; m >>= 1) {
            s += __shfl_xor(s, m);
            t += __shfl_xor(t, m);
        }
        float mean = s * (1.f / EMB);
        float var = t * (1.f / EMB) - mean * mean;
        float rstd = rsqrtf(var + 1e-5f);
        float xo[8];
#pragma unroll
        for (int j = 0; j < 8; j++) {
            int col = lane * 8 + j;
            xo[j] = (v[j] - mean) * rstd * gam[col] + bet[col];
        }
        float* op = out + grow * EMB + lane * 8;
        *(float4*)op = make_float4(xo[0], xo[1], xo[2], xo[3]);
        *(float4*)(op + 4) = make_float4(xo[4], xo[5], xo[6], xo[7]);
    }
}

// ---------------- launch ----------------

extern "C" void kernel_launch(void* const* d_in, const int* in_sizes, int n_in,
                              void* d_out, int out_size, void* d_ws, size_t ws_size,
                              hipStream_t stream) {
    (void)in_sizes; (void)n_in; (void)out_size; (void)ws_size;
    const float* q     = (const float*)d_in[0];
    const float* k     = (const float*)d_in[1];
    const float* v_W   = (const float*)d_in[3];
    const float* v_b   = (const float*)d_in[4];
    const float* out_W = (const float*)d_in[5];
    const float* out_b = (const float*)d_in[6];
    const float* ln1_g = (const float*)d_in[7];
    const float* ln1_b = (const float*)d_in[8];
    const float* w1    = (const float*)d_in[9];
    const float* b1    = (const float*)d_in[10];
    const float* w2    = (const float*)d_in[11];
    const float* b2    = (const float*)d_in[12];
    const float* ln2_g = (const float*)d_in[13];
    const float* ln2_b = (const float*)d_in[14];

    char* ws = (char*)d_ws;
    const size_t MB = 1u << 20;
    short* SK   = (short*)(ws);            // 16MB bf16 suffix-mean of k
    short* T1   = (short*)(ws + 16 * MB);  // 16MB bf16 SK@v_W + v_b
    short* VO2  = (short*)(ws + 32 * MB);  // 16MB bf16 T1@out_W + out_b
    short* Xbf  = (short*)(ws + 48 * MB);  // 16MB bf16 x (post-LN1)
    short* H1   = (short*)(ws + 64 * MB);  // 16MB bf16 relu(x@w1+b1)
    short* Y    = (short*)(ws + 80 * MB);  // 16MB bf16 h1@w2+b2
    short* VvT  = (short*)(ws + 96 * MB);  // v_W^T bf16
    short* WoT  = VvT + 512 * 512;         // out_W^T bf16
    short* W1T  = WoT + 512 * 512;
    short* W2T  = W1T + 512 * 512;
    float* part = (float*)(W2T + 512 * 512);  // 8*32*512 f32 chunk partials

    prep_all<<<512, 256, 0, stream>>>(v_W, out_W, w1, w2, VvT, WoT, W1T, W2T);
    // suffix-mean of k
    scan_p1<<<BATCH * NCH, 256, 0, stream>>>(k, part);
    scan_p2<<<BATCH * NCH, 256, 0, stream>>>(k, part, SK);
    // T1 = SK @ v_W + v_b
    mgemm<0><<<(BS / 128) * 4, 256, 0, stream>>>(SK, VvT, v_b, T1);
    // attn_out = T1 @ out_W + out_b
    mgemm<0><<<(BS / 128) * 4, 256, 0, stream>>>(T1, WoT, out_b, VO2);
    // x = LN1(q + attn_out)
    ln1_kernel<<<BS / 32, 256, 0, stream>>>(q, VO2, ln1_g, ln1_b, Xbf);
    // h1 = relu(x @ w1 + b1)
    mgemm<1><<<(BS / 128) * 4, 256, 0, stream>>>(Xbf, W1T, b1, H1);
    // y = h1 @ w2 + b2
    mgemm<0><<<(BS / 128) * 4, 256, 0, stream>>>(H1, W2T, b2, Y);
    // out = LN2(x + y)
    ln2_kernel<<<BS / 32, 256, 0, stream>>>(Xbf, Y, ln2_g, ln2_b, (float*)d_out);
}